// Round 1
// baseline (857.069 us; speedup 1.0000x reference)
//
#include <hip/hip_runtime.h>

typedef __bf16 bf16x8 __attribute__((ext_vector_type(8)));
typedef __bf16 bf16x4 __attribute__((ext_vector_type(4)));
typedef float f32x4 __attribute__((ext_vector_type(4)));

#define MFMA_16x16x32_BF16(a, b, c) __builtin_amdgcn_mfma_f32_16x16x32_bf16(a, b, c, 0, 0, 0)

typedef const __attribute__((address_space(1))) unsigned int* gas_ptr;
typedef __attribute__((address_space(3))) unsigned int* las_ptr;

__device__ __forceinline__ void gload_lds16(const void* g, void* l) {
    __builtin_amdgcn_global_load_lds((gas_ptr)(unsigned long long)g,
                                     (las_ptr)(unsigned long long)l, 16, 0, 0);
}

// m-major ordering permutation: xm[:, b] = x[:, ORDER[b]]; out[:, ORDER[a]] = gemm_out[:, a]
__constant__ int ORDER_C[19] = {0, 2, 6, 11, 16, 3, 7, 12, 17, 1, 5, 10, 15, 8, 13, 18, 4, 9, 14};

// ---------------------------------------------------------------------------
// Kernel 1: fused weight conversion (1024 blocks) + x_edge conversion (4096).
// ---------------------------------------------------------------------------
__global__ __launch_bounds__(256) void wxconv_kernel(
    const float* __restrict__ fc0, const float* __restrict__ fc1,
    const float* __restrict__ fc2, const float* __restrict__ rw1,
    const float* __restrict__ rw2, const float* __restrict__ rw3,
    const float* __restrict__ xe, __bf16* __restrict__ wo,
    __bf16* __restrict__ xo) {
    const int bid = blockIdx.x;
    const float* s;
    __bf16* o;
    int i4, rel;
    if (bid < 1024) {
        i4 = (bid * 256 + threadIdx.x) * 4;
        o = wo;
        if (i4 < 409600)      { s = fc0; rel = i4; }
        else if (i4 < 671744) { s = fc1; rel = i4 - 409600; }
        else if (i4 < 819200) { s = fc2; rel = i4 - 671744; }
        else if (i4 < 835584) { s = rw1; rel = i4 - 819200; }
        else if (i4 < 851968) { s = rw2; rel = i4 - 835584; }
        else                  { s = rw3; rel = i4 - 851968; }
    } else {
        i4 = ((bid - 1024) * 256 + threadIdx.x) * 4;
        o = xo; s = xe; rel = i4;
    }
    float4 v = *(const float4*)(s + rel);
    bf16x4 b;
    b[0] = (__bf16)v.x; b[1] = (__bf16)v.y; b[2] = (__bf16)v.z; b[3] = (__bf16)v.w;
    *(bf16x4*)(o + i4) = b;
}

// ---------------------------------------------------------------------------
// Kernel 2: fused [N,128]@W[128,128]^T + bias + LayerNorm + SiLU -> bf16.
// XOR-swizzled LDS (st-style, row&15 on 256B rows). grid N/128, block 256.
// LN epilogue reuses As+Bs (64KB) as a fp32 [128][128] staging buffer.
// ---------------------------------------------------------------------------
__global__ __launch_bounds__(256) void gemmln_kernel(
    const __bf16* __restrict__ Ain, const __bf16* __restrict__ Wb,
    const float* __restrict__ bvec, const float* __restrict__ gv,
    const float* __restrict__ bev, __bf16* __restrict__ hs) {
    __shared__ __align__(16) char smem[65536];
    __bf16* As = (__bf16*)smem;
    __bf16* Bs = (__bf16*)(smem + 32768);
    float*  Fs = (float*)smem;          // aliases As+Bs, used post-barrier
    const int tid = threadIdx.x;
    const int w = tid >> 6, lane = tid & 63;
    const int quad = lane >> 4, l16 = lane & 15;
    const int e0 = blockIdx.x * 128;

    {
        const char* ga = (const char*)(Ain + (size_t)e0 * 128);
        const char* gb = (const char*)Wb;
        for (int r = 0; r < 8; ++r) {
            int boff = (r * 4 + w) * 1024 + lane * 16;
            int soff = boff ^ (((boff >> 8) & 15) << 4);   // pre-swizzled source
            gload_lds16(ga + soff, (char*)As + boff);
            gload_lds16(gb + soff, (char*)Bs + boff);
        }
    }
    __syncthreads();

    const int wr = w >> 1, wc = w & 1;
    f32x4 acc[4][4] = {};
    for (int ks = 0; ks < 4; ++ks) {
        bf16x8 af[4], bfr[4];
        for (int i = 0; i < 4; ++i) {
            int ar = wr * 64 + i * 16 + l16;
            af[i] = *(const bf16x8*)&As[ar * 128 + ((ks * 32 + quad * 8) ^ ((ar & 15) << 3))];
        }
        for (int j = 0; j < 4; ++j) {
            int br = wc * 64 + j * 16 + l16;
            bfr[j] = *(const bf16x8*)&Bs[br * 128 + ((ks * 32 + quad * 8) ^ ((br & 15) << 3))];
        }
        for (int i = 0; i < 4; ++i)
            for (int j = 0; j < 4; ++j)
                acc[i][j] = MFMA_16x16x32_BF16(af[i], bfr[j], acc[i][j]);
    }
    __syncthreads();   // all fragment reads done; smem becomes Fs

    float bc[4];
    for (int j = 0; j < 4; ++j) bc[j] = bvec[wc * 64 + j * 16 + l16];
    for (int i = 0; i < 4; ++i)
        for (int j = 0; j < 4; ++j)
            for (int r = 0; r < 4; ++r)
                Fs[(wr * 64 + i * 16 + quad * 4 + r) * 128 + wc * 64 + j * 16 + l16] =
                    acc[i][j][r] + bc[j];
    __syncthreads();

    const float gl = gv[lane], gh = gv[lane + 64];
    const float bl = bev[lane], bh = bev[lane + 64];
    for (int it = 0; it < 32; ++it) {
        const int row = it * 4 + w;
        float a = Fs[row * 128 + lane];
        float b = Fs[row * 128 + lane + 64];
        float s = a + b;
        s += __shfl_xor(s, 1);  s += __shfl_xor(s, 2);  s += __shfl_xor(s, 4);
        s += __shfl_xor(s, 8);  s += __shfl_xor(s, 16); s += __shfl_xor(s, 32);
        const float mu = s * (1.f / 128.f);
        const float da = a - mu, db = b - mu;
        float v = da * da + db * db;
        v += __shfl_xor(v, 1);  v += __shfl_xor(v, 2);  v += __shfl_xor(v, 4);
        v += __shfl_xor(v, 8);  v += __shfl_xor(v, 16); v += __shfl_xor(v, 32);
        const float rs = rsqrtf(v * (1.f / 128.f) + 1e-5f);
        float ya = da * rs * gl + bl;
        float yb = db * rs * gh + bh;
        ya = ya / (1.f + __expf(-ya));
        yb = yb / (1.f + __expf(-yb));
        hs[(size_t)(e0 + row) * 128 + lane] = (__bf16)ya;
        hs[(size_t)(e0 + row) * 128 + lane + 64] = (__bf16)yb;
    }
}

// ---------------------------------------------------------------------------
// Kernel 3: rad = h2 @ w3^T + b3 -> bf16 [N,1536]. grid (N/128, 12), 256 thr.
// Swizzled LDS like gemmln.
// ---------------------------------------------------------------------------
__global__ __launch_bounds__(256) void radial3_kernel(
    const __bf16* __restrict__ h2g, const __bf16* __restrict__ w3b,
    const float* __restrict__ b3, __bf16* __restrict__ radg) {
    __shared__ __align__(16) __bf16 As[128 * 128];
    __shared__ __align__(16) __bf16 Bs[128 * 128];
    const int tid = threadIdx.x;
    const int w = tid >> 6, lane = tid & 63;
    const int quad = lane >> 4, l16 = lane & 15;
    const int e0 = blockIdx.x * 128, n0 = blockIdx.y * 128;

    {
        const char* ga = (const char*)(h2g + (size_t)e0 * 128);
        const char* gb = (const char*)(w3b + (size_t)n0 * 128);
        for (int r = 0; r < 8; ++r) {
            int boff = (r * 4 + w) * 1024 + lane * 16;
            int soff = boff ^ (((boff >> 8) & 15) << 4);
            gload_lds16(ga + soff, (char*)As + boff);
            gload_lds16(gb + soff, (char*)Bs + boff);
        }
    }
    __syncthreads();

    const int wr = w >> 1, wc = w & 1;
    f32x4 acc[4][4] = {};
    for (int ks = 0; ks < 4; ++ks) {
        bf16x8 af[4], bfr[4];
        for (int i = 0; i < 4; ++i) {
            int ar = wr * 64 + i * 16 + l16;
            af[i] = *(const bf16x8*)&As[ar * 128 + ((ks * 32 + quad * 8) ^ ((ar & 15) << 3))];
        }
        for (int j = 0; j < 4; ++j) {
            int br = wc * 64 + j * 16 + l16;
            bfr[j] = *(const bf16x8*)&Bs[br * 128 + ((ks * 32 + quad * 8) ^ ((br & 15) << 3))];
        }
        for (int i = 0; i < 4; ++i)
            for (int j = 0; j < 4; ++j)
                acc[i][j] = MFMA_16x16x32_BF16(af[i], bfr[j], acc[i][j]);
    }
    __syncthreads();   // frag reads done; reuse As as output staging (linear)

    float bcol[4];
    for (int j = 0; j < 4; ++j) bcol[j] = b3[n0 + wc * 64 + j * 16 + l16];
    for (int i = 0; i < 4; ++i)
        for (int j = 0; j < 4; ++j)
            for (int r = 0; r < 4; ++r) {
                int row = wr * 64 + i * 16 + quad * 4 + r;
                int col = wc * 64 + j * 16 + l16;
                As[row * 128 + col] = (__bf16)(acc[i][j][r] + bcol[j]);
            }
    __syncthreads();
    for (int r = 0; r < 8; ++r) {
        int idx = r * 256 + tid;
        int e = idx >> 4, c = (idx & 15) * 8;
        *(uint4*)(radg + (size_t)(e0 + e) * 1536 + n0 + c) = *(const uint4*)&As[e * 128 + c];
    }
}

// ---------------------------------------------------------------------------
// Kernel 4: main fused FiLM-GEMM, group-fused. grid (N/128, 5). blockIdx.y is
// one SO(2) group: {m0, m1+, m1-, m2+, m2-}; the block loops all sz output
// rows of its group internally, so the group's x/rad/W slices stay L2-hot.
// XOR-swizzled 64-wide LDS tiles (row&7, 128B rows).
// ---------------------------------------------------------------------------
__global__ __launch_bounds__(256) void so2_main_kernel(
    const float* __restrict__ xg, const __bf16* __restrict__ radg,
    const __bf16* __restrict__ wfc0, const __bf16* __restrict__ wfc1,
    const __bf16* __restrict__ wfc2, const float* __restrict__ fc0b,
    float* __restrict__ outg) {
    __shared__ __align__(16) __bf16 As[128 * 64];   // [edge][k], swizzled
    __shared__ __align__(16) __bf16 Bs[128 * 64];   // [outcol][k], swizzled
    const int tid = threadIdx.x;
    const int w = tid >> 6, lane = tid & 63;
    const int quad = lane >> 4, l16 = lane & 15;
    const int e0 = blockIdx.x * 128;
    const int gid = blockIdx.y;

    const int bstart = (gid == 0) ? 0 : (gid == 1) ? 5 : (gid == 2) ? 9 : (gid == 3) ? 13 : 16;
    const int sz     = (gid == 0) ? 5 : (gid < 3) ? 4 : 3;
    const int rado   = (gid == 0) ? 0 : (gid < 3) ? 640 : 1152;
    const int K      = sz * 128;
    const __bf16* W  = (gid == 0) ? wfc0 : (gid < 3) ? wfc1 : wfc2;

    const int wr = w >> 1, wc = w & 1;
    const int e_ = tid >> 4;           // 0..15, +r*16 per staging round
    const int cA = (tid & 15) * 4;     // k within 64-wide tile, 4 elems/lane

    for (int so = 0; so < sz; ++so) {
        f32x4 acc[4][4] = {};
        const char* wbase = (const char*)W + ((size_t)so * 128 * K) * 2;
        const int nkt = 2 * sz;
        for (int kt = 0; kt < nkt; ++kt) {
            const int s_in = kt >> 1, cb = (kt & 1) * 64;
            const int xrow = ORDER_C[bstart + s_in];
            // ---- A staging: FiLM (x fp32 * rad bf16) -> bf16 LDS, swizzled write
            {
                const float* xp = xg + (size_t)(e0 + e_) * 2432 + xrow * 128 + cb + cA;
                const __bf16* rp = radg + (size_t)(e0 + e_) * 1536 + rado + s_in * 128 + cb + cA;
                for (int r = 0; r < 8; ++r) {
                    float4 xv = *(const float4*)(xp + (size_t)r * 16 * 2432);
                    bf16x4 rv = *(const bf16x4*)(rp + (size_t)r * 16 * 1536);
                    bf16x4 av;
                    av[0] = (__bf16)(xv.x * (float)rv[0]);
                    av[1] = (__bf16)(xv.y * (float)rv[1]);
                    av[2] = (__bf16)(xv.z * (float)rv[2]);
                    av[3] = (__bf16)(xv.w * (float)rv[3]);
                    const int arow = e_ + r * 16;
                    *(bf16x4*)&As[arow * 64 + (cA ^ ((arow & 7) << 3))] = av;
                }
            }
            // ---- B staging: linear LDS dest, pre-swizzled global source
            {
                const char* wkt = wbase + (size_t)kt * 128;   // kt*64 elems * 2B
                for (int r = 0; r < 4; ++r) {
                    int boff = (r * 4 + w) * 1024 + lane * 16;
                    int col = boff >> 7, kb = boff & 127;
                    gload_lds16(wkt + (size_t)col * K * 2 + (kb ^ ((col & 7) << 4)),
                                (char*)Bs + boff);
                }
            }
            __syncthreads();
            for (int ks = 0; ks < 2; ++ks) {
                bf16x8 af[4], bfr[4];
                for (int i = 0; i < 4; ++i) {
                    int ar = wr * 64 + i * 16 + l16;
                    af[i] = *(const bf16x8*)&As[ar * 64 + ((ks * 32 + quad * 8) ^ ((ar & 7) << 3))];
                }
                for (int j = 0; j < 4; ++j) {
                    int br = wc * 64 + j * 16 + l16;
                    bfr[j] = *(const bf16x8*)&Bs[br * 64 + ((ks * 32 + quad * 8) ^ ((br & 7) << 3))];
                }
                for (int i = 0; i < 4; ++i)
                    for (int j = 0; j < 4; ++j)
                        acc[i][j] = MFMA_16x16x32_BF16(af[i], bfr[j], acc[i][j]);
            }
            __syncthreads();
        }

        // epilogue: bias (m0 only) + inverse-permuted store, fp32
        const int outrow = ORDER_C[bstart + so];
        float bv[4];
        for (int j = 0; j < 4; ++j)
            bv[j] = (gid == 0) ? fc0b[so * 128 + wc * 64 + j * 16 + l16] : 0.f;
        for (int i = 0; i < 4; ++i)
            for (int j = 0; j < 4; ++j) {
                const int col = wc * 64 + j * 16 + l16;
                for (int r = 0; r < 4; ++r) {
                    const int row = e0 + wr * 64 + i * 16 + quad * 4 + r;
                    outg[(size_t)row * 2432 + outrow * 128 + col] = acc[i][j][r] + bv[j];
                }
            }
    }
}

// ---------------------------------------------------------------------------
extern "C" void kernel_launch(void* const* d_in, const int* in_sizes, int n_in,
                              void* d_out, int out_size, void* d_ws, size_t ws_size,
                              hipStream_t stream) {
    const float* x       = (const float*)d_in[0];
    const float* x_edge  = (const float*)d_in[1];
    const float* fc0_w   = (const float*)d_in[2];
    const float* fc0_b   = (const float*)d_in[3];
    const float* fc1_w   = (const float*)d_in[4];
    const float* fc2_w   = (const float*)d_in[5];
    const float* rad_w1  = (const float*)d_in[6];
    const float* rad_b1  = (const float*)d_in[7];
    const float* rad_g1  = (const float*)d_in[8];
    const float* rad_be1 = (const float*)d_in[9];
    const float* rad_w2  = (const float*)d_in[10];
    const float* rad_b2  = (const float*)d_in[11];
    const float* rad_g2  = (const float*)d_in[12];
    const float* rad_be2 = (const float*)d_in[13];
    const float* rad_w3  = (const float*)d_in[14];
    const float* rad_b3  = (const float*)d_in[15];
    float* out = (float*)d_out;

    const int N = in_sizes[0] / (19 * 128);   // 32768

    // workspace layout (106 MB):
    //   [0, 2MB)    wb  : bf16 weights
    //   [2, 10MB)   sh  : xeb -> (h1 lives in rad region) -> h2 (8MB)
    //   [10,106MB)  rad : bf16 [N,1536]; first 8MB holds h1 transiently
    //                     (dead before radial3 overwrites it with rad)
    __bf16* wb  = (__bf16*)d_ws;
    __bf16* sh  = (__bf16*)((char*)d_ws + (2u << 20));
    __bf16* rb  = (__bf16*)((char*)d_ws + (10u << 20));
    __bf16* h1  = rb;
    __bf16* rad = rb;
    __bf16* wfc0 = wb;
    __bf16* wfc1 = wb + 409600;
    __bf16* wfc2 = wb + 671744;
    __bf16* w1b  = wb + 819200;
    __bf16* w2b  = wb + 835584;
    __bf16* w3b  = wb + 851968;

    wxconv_kernel<<<dim3(5120), dim3(256), 0, stream>>>(fc0_w, fc1_w, fc2_w, rad_w1,
                                                        rad_w2, rad_w3, x_edge, wb, sh);
    gemmln_kernel<<<dim3(N / 128), dim3(256), 0, stream>>>(sh, w1b, rad_b1, rad_g1,
                                                           rad_be1, h1);
    gemmln_kernel<<<dim3(N / 128), dim3(256), 0, stream>>>(h1, w2b, rad_b2, rad_g2,
                                                           rad_be2, sh);
    radial3_kernel<<<dim3(N / 128, 12), dim3(256), 0, stream>>>(sh, w3b, rad_b3, rad);
    so2_main_kernel<<<dim3(N / 128, 5), dim3(256), 0, stream>>>(x, rad, wfc0, wfc1, wfc2,
                                                                fc0_b, out);
}

// Round 2
// 760.685 us; speedup vs baseline: 1.1267x; 1.1267x over previous
//
#include <hip/hip_runtime.h>

typedef __bf16 bf16x8 __attribute__((ext_vector_type(8)));
typedef __bf16 bf16x4 __attribute__((ext_vector_type(4)));
typedef float f32x4 __attribute__((ext_vector_type(4)));

#define MFMA_16x16x32_BF16(a, b, c) __builtin_amdgcn_mfma_f32_16x16x32_bf16(a, b, c, 0, 0, 0)

typedef const __attribute__((address_space(1))) unsigned int* gas_ptr;
typedef __attribute__((address_space(3))) unsigned int* las_ptr;

__device__ __forceinline__ void gload_lds16(const void* g, void* l) {
    __builtin_amdgcn_global_load_lds((gas_ptr)(unsigned long long)g,
                                     (las_ptr)(unsigned long long)l, 16, 0, 0);
}

// m-major ordering permutation: xm[:, b] = x[:, ORDER[b]]; out[:, ORDER[a]] = gemm_out[:, a]
__constant__ int ORDER_C[19] = {0, 2, 6, 11, 16, 3, 7, 12, 17, 1, 5, 10, 15, 8, 13, 18, 4, 9, 14};

// ---------------------------------------------------------------------------
// Kernel 1: fused weight conversion (1024 blocks) + x_edge conversion (4096).
// ---------------------------------------------------------------------------
__global__ __launch_bounds__(256) void wxconv_kernel(
    const float* __restrict__ fc0, const float* __restrict__ fc1,
    const float* __restrict__ fc2, const float* __restrict__ rw1,
    const float* __restrict__ rw2, const float* __restrict__ rw3,
    const float* __restrict__ xe, __bf16* __restrict__ wo,
    __bf16* __restrict__ xo) {
    const int bid = blockIdx.x;
    const float* s;
    __bf16* o;
    int i4, rel;
    if (bid < 1024) {
        i4 = (bid * 256 + threadIdx.x) * 4;
        o = wo;
        if (i4 < 409600)      { s = fc0; rel = i4; }
        else if (i4 < 671744) { s = fc1; rel = i4 - 409600; }
        else if (i4 < 819200) { s = fc2; rel = i4 - 671744; }
        else if (i4 < 835584) { s = rw1; rel = i4 - 819200; }
        else if (i4 < 851968) { s = rw2; rel = i4 - 835584; }
        else                  { s = rw3; rel = i4 - 851968; }
    } else {
        i4 = ((bid - 1024) * 256 + threadIdx.x) * 4;
        o = xo; s = xe; rel = i4;
    }
    float4 v = *(const float4*)(s + rel);
    bf16x4 b;
    b[0] = (__bf16)v.x; b[1] = (__bf16)v.y; b[2] = (__bf16)v.z; b[3] = (__bf16)v.w;
    *(bf16x4*)(o + i4) = b;
}

// ---------------------------------------------------------------------------
// Kernel 2: fused [N,128]@W[128,128]^T + bias + LayerNorm + SiLU -> bf16.
// XOR-swizzled LDS. grid N/128, block 256. (validated round 1)
// ---------------------------------------------------------------------------
__global__ __launch_bounds__(256) void gemmln_kernel(
    const __bf16* __restrict__ Ain, const __bf16* __restrict__ Wb,
    const float* __restrict__ bvec, const float* __restrict__ gv,
    const float* __restrict__ bev, __bf16* __restrict__ hs) {
    __shared__ __align__(16) char smem[65536];
    __bf16* As = (__bf16*)smem;
    __bf16* Bs = (__bf16*)(smem + 32768);
    float*  Fs = (float*)smem;          // aliases As+Bs, used post-barrier
    const int tid = threadIdx.x;
    const int w = tid >> 6, lane = tid & 63;
    const int quad = lane >> 4, l16 = lane & 15;
    const int e0 = blockIdx.x * 128;

    {
        const char* ga = (const char*)(Ain + (size_t)e0 * 128);
        const char* gb = (const char*)Wb;
        for (int r = 0; r < 8; ++r) {
            int boff = (r * 4 + w) * 1024 + lane * 16;
            int soff = boff ^ (((boff >> 8) & 15) << 4);   // pre-swizzled source
            gload_lds16(ga + soff, (char*)As + boff);
            gload_lds16(gb + soff, (char*)Bs + boff);
        }
    }
    __syncthreads();

    const int wr = w >> 1, wc = w & 1;
    f32x4 acc[4][4] = {};
    for (int ks = 0; ks < 4; ++ks) {
        bf16x8 af[4], bfr[4];
        for (int i = 0; i < 4; ++i) {
            int ar = wr * 64 + i * 16 + l16;
            af[i] = *(const bf16x8*)&As[ar * 128 + ((ks * 32 + quad * 8) ^ ((ar & 15) << 3))];
        }
        for (int j = 0; j < 4; ++j) {
            int br = wc * 64 + j * 16 + l16;
            bfr[j] = *(const bf16x8*)&Bs[br * 128 + ((ks * 32 + quad * 8) ^ ((br & 15) << 3))];
        }
        for (int i = 0; i < 4; ++i)
            for (int j = 0; j < 4; ++j)
                acc[i][j] = MFMA_16x16x32_BF16(af[i], bfr[j], acc[i][j]);
    }
    __syncthreads();   // all fragment reads done; smem becomes Fs

    float bc[4];
    for (int j = 0; j < 4; ++j) bc[j] = bvec[wc * 64 + j * 16 + l16];
    for (int i = 0; i < 4; ++i)
        for (int j = 0; j < 4; ++j)
            for (int r = 0; r < 4; ++r)
                Fs[(wr * 64 + i * 16 + quad * 4 + r) * 128 + wc * 64 + j * 16 + l16] =
                    acc[i][j][r] + bc[j];
    __syncthreads();

    const float gl = gv[lane], gh = gv[lane + 64];
    const float bl = bev[lane], bh = bev[lane + 64];
    for (int it = 0; it < 32; ++it) {
        const int row = it * 4 + w;
        float a = Fs[row * 128 + lane];
        float b = Fs[row * 128 + lane + 64];
        float s = a + b;
        s += __shfl_xor(s, 1);  s += __shfl_xor(s, 2);  s += __shfl_xor(s, 4);
        s += __shfl_xor(s, 8);  s += __shfl_xor(s, 16); s += __shfl_xor(s, 32);
        const float mu = s * (1.f / 128.f);
        const float da = a - mu, db = b - mu;
        float v = da * da + db * db;
        v += __shfl_xor(v, 1);  v += __shfl_xor(v, 2);  v += __shfl_xor(v, 4);
        v += __shfl_xor(v, 8);  v += __shfl_xor(v, 16); v += __shfl_xor(v, 32);
        const float rs = rsqrtf(v * (1.f / 128.f) + 1e-5f);
        float ya = da * rs * gl + bl;
        float yb = db * rs * gh + bh;
        ya = ya / (1.f + __expf(-ya));
        yb = yb / (1.f + __expf(-yb));
        hs[(size_t)(e0 + row) * 128 + lane] = (__bf16)ya;
        hs[(size_t)(e0 + row) * 128 + lane + 64] = (__bf16)yb;
    }
}

// ---------------------------------------------------------------------------
// Kernel 3: radial3 + fused FiLM. grid (N/128, 12), 256 thr.
// GEMM: rad_tile = h2 @ w3^T + b3 (bf16, staged in LDS).
// Epilogue: A[n, b, c] = x[n, ORDER[b], c] * rad_tile  for the 1-2 m-major
// coefficient rows b that this rad column block feeds. Eliminates the rad
// round-trip entirely; x is read exactly once across the whole grid.
// ---------------------------------------------------------------------------
__global__ __launch_bounds__(256) void radial3_film_kernel(
    const __bf16* __restrict__ h2g, const __bf16* __restrict__ w3b,
    const float* __restrict__ b3, const float* __restrict__ xg,
    __bf16* __restrict__ Aws) {
    __shared__ __align__(16) __bf16 As[128 * 128];
    __shared__ __align__(16) __bf16 Bs[128 * 128];
    const int tid = threadIdx.x;
    const int w = tid >> 6, lane = tid & 63;
    const int quad = lane >> 4, l16 = lane & 15;
    const int y = blockIdx.y;
    const int e0 = blockIdx.x * 128, n0 = y * 128;

    {
        const char* ga = (const char*)(h2g + (size_t)e0 * 128);
        const char* gb = (const char*)(w3b + (size_t)n0 * 128);
        for (int r = 0; r < 8; ++r) {
            int boff = (r * 4 + w) * 1024 + lane * 16;
            int soff = boff ^ (((boff >> 8) & 15) << 4);
            gload_lds16(ga + soff, (char*)As + boff);
            gload_lds16(gb + soff, (char*)Bs + boff);
        }
    }
    __syncthreads();

    const int wr = w >> 1, wc = w & 1;
    f32x4 acc[4][4] = {};
    for (int ks = 0; ks < 4; ++ks) {
        bf16x8 af[4], bfr[4];
        for (int i = 0; i < 4; ++i) {
            int ar = wr * 64 + i * 16 + l16;
            af[i] = *(const bf16x8*)&As[ar * 128 + ((ks * 32 + quad * 8) ^ ((ar & 15) << 3))];
        }
        for (int j = 0; j < 4; ++j) {
            int br = wc * 64 + j * 16 + l16;
            bfr[j] = *(const bf16x8*)&Bs[br * 128 + ((ks * 32 + quad * 8) ^ ((br & 15) << 3))];
        }
        for (int i = 0; i < 4; ++i)
            for (int j = 0; j < 4; ++j)
                acc[i][j] = MFMA_16x16x32_BF16(af[i], bfr[j], acc[i][j]);
    }
    __syncthreads();   // frag reads done; reuse As as rad staging (linear)

    float bcol[4];
    for (int j = 0; j < 4; ++j) bcol[j] = b3[n0 + wc * 64 + j * 16 + l16];
    for (int i = 0; i < 4; ++i)
        for (int j = 0; j < 4; ++j)
            for (int r = 0; r < 4; ++r) {
                int row = wr * 64 + i * 16 + quad * 4 + r;
                int col = wc * 64 + j * 16 + l16;
                As[row * 128 + col] = (__bf16)(acc[i][j][r] + bcol[j]);
            }
    __syncthreads();

    // FiLM epilogue: rad col block n0 feeds coefficient rows:
    //   y<5  : b=y            (m=0)
    //   y<9  : b=y, y+4       (m=+1 / m=-1 share the rad slice)
    //   else : b=y+4, y+7     (m=+2 / m=-2)
    int nb, bs0, bs1;
    if (y < 5)      { nb = 1; bs0 = y;     bs1 = 0; }
    else if (y < 9) { nb = 2; bs0 = y;     bs1 = y + 4; }
    else            { nb = 2; bs0 = y + 4; bs1 = y + 7; }

    for (int t = 0; t < nb; ++t) {
        const int b = t ? bs1 : bs0;
        const int xrow = ORDER_C[b];
        for (int r = 0; r < 8; ++r) {
            int idx = r * 256 + tid;
            int e = idx >> 4, c = (idx & 15) * 8;
            bf16x8 rv = *(const bf16x8*)&As[e * 128 + c];
            const float* xp = xg + (size_t)(e0 + e) * 2432 + xrow * 128 + c;
            float4 x0 = *(const float4*)xp;
            float4 x1 = *(const float4*)(xp + 4);
            bf16x8 av;
            av[0] = (__bf16)(x0.x * (float)rv[0]);
            av[1] = (__bf16)(x0.y * (float)rv[1]);
            av[2] = (__bf16)(x0.z * (float)rv[2]);
            av[3] = (__bf16)(x0.w * (float)rv[3]);
            av[4] = (__bf16)(x1.x * (float)rv[4]);
            av[5] = (__bf16)(x1.y * (float)rv[5]);
            av[6] = (__bf16)(x1.z * (float)rv[6]);
            av[7] = (__bf16)(x1.w * (float)rv[7]);
            *(bf16x8*)(Aws + (size_t)(e0 + e) * 2432 + b * 128 + c) = av;
        }
    }
}

// ---------------------------------------------------------------------------
// Kernel 4: main GEMM, now pure bf16 (FiLM pre-applied). grid (N/128, 19).
// Both operands staged via global_load_lds with pre-swizzled source; LDS
// double-buffered (2-phase pipeline: next-tile loads fly under MFMA).
// ---------------------------------------------------------------------------
__global__ __launch_bounds__(256) void so2_gemm_kernel(
    const __bf16* __restrict__ Aws, const __bf16* __restrict__ wfc0,
    const __bf16* __restrict__ wfc1, const __bf16* __restrict__ wfc2,
    const float* __restrict__ fc0b, float* __restrict__ outg) {
    __shared__ __align__(16) __bf16 As[2][128 * 64];
    __shared__ __align__(16) __bf16 Bs[2][128 * 64];
    const int tid = threadIdx.x;
    const int w = tid >> 6, lane = tid & 63;
    const int quad = lane >> 4, l16 = lane & 15;
    const int e0 = blockIdx.x * 128;
    const int y = blockIdx.y;

    int bstart, sz;
    const __bf16* W;
    if (y < 5)       { bstart = 0;  sz = 5; W = wfc0; }
    else if (y < 9)  { bstart = 5;  sz = 4; W = wfc1; }
    else if (y < 13) { bstart = 9;  sz = 4; W = wfc1; }
    else if (y < 16) { bstart = 13; sz = 3; W = wfc2; }
    else             { bstart = 16; sz = 3; W = wfc2; }
    const int K = sz * 128, s_out = y - bstart, nkt = 2 * sz;
    const char* abase = (const char*)Aws + (size_t)bstart * 256;
    const char* wbase = (const char*)W + (size_t)s_out * 128 * K * 2;

#define STAGE(buf, kt)                                                             \
    {                                                                              \
        const char* ak = abase + (size_t)(kt) * 128;                               \
        const char* wk = wbase + (size_t)(kt) * 128;                               \
        for (int r = 0; r < 4; ++r) {                                              \
            int boff = (r * 4 + w) * 1024 + lane * 16;                             \
            int row = boff >> 7, kb = boff & 127;                                  \
            int skb = kb ^ ((row & 7) << 4);                                       \
            gload_lds16(ak + (size_t)(e0 + row) * 4864 + skb, (char*)As[buf] + boff); \
            gload_lds16(wk + (size_t)row * (size_t)(K * 2) + skb, (char*)Bs[buf] + boff); \
        }                                                                          \
    }

    const int wr = w >> 1, wc = w & 1;
    f32x4 acc[4][4] = {};
    STAGE(0, 0);
    __syncthreads();
    for (int kt = 0; kt < nkt; ++kt) {
        const int cur = kt & 1;
        if (kt + 1 < nkt) STAGE(cur ^ 1, kt + 1);
        for (int ks = 0; ks < 2; ++ks) {
            bf16x8 af[4], bfr[4];
            for (int i = 0; i < 4; ++i) {
                int ar = wr * 64 + i * 16 + l16;
                af[i] = *(const bf16x8*)&As[cur][ar * 64 + ((ks * 32 + quad * 8) ^ ((ar & 7) << 3))];
            }
            for (int j = 0; j < 4; ++j) {
                int br = wc * 64 + j * 16 + l16;
                bfr[j] = *(const bf16x8*)&Bs[cur][br * 64 + ((ks * 32 + quad * 8) ^ ((br & 7) << 3))];
            }
            for (int i = 0; i < 4; ++i)
                for (int j = 0; j < 4; ++j)
                    acc[i][j] = MFMA_16x16x32_BF16(af[i], bfr[j], acc[i][j]);
        }
        __syncthreads();
    }
#undef STAGE

    // epilogue: bias (m0 only) + inverse-permuted store, fp32
    const int outrow = ORDER_C[y];
    float bv[4];
    for (int j = 0; j < 4; ++j)
        bv[j] = (y < 5) ? fc0b[s_out * 128 + wc * 64 + j * 16 + l16] : 0.f;
    for (int i = 0; i < 4; ++i)
        for (int j = 0; j < 4; ++j) {
            const int col = wc * 64 + j * 16 + l16;
            for (int r = 0; r < 4; ++r) {
                const int row = e0 + wr * 64 + i * 16 + quad * 4 + r;
                outg[(size_t)row * 2432 + outrow * 128 + col] = acc[i][j][r] + bv[j];
            }
        }
}

// ---------------------------------------------------------------------------
extern "C" void kernel_launch(void* const* d_in, const int* in_sizes, int n_in,
                              void* d_out, int out_size, void* d_ws, size_t ws_size,
                              hipStream_t stream) {
    const float* x       = (const float*)d_in[0];
    const float* x_edge  = (const float*)d_in[1];
    const float* fc0_w   = (const float*)d_in[2];
    const float* fc0_b   = (const float*)d_in[3];
    const float* fc1_w   = (const float*)d_in[4];
    const float* fc2_w   = (const float*)d_in[5];
    const float* rad_w1  = (const float*)d_in[6];
    const float* rad_b1  = (const float*)d_in[7];
    const float* rad_g1  = (const float*)d_in[8];
    const float* rad_be1 = (const float*)d_in[9];
    const float* rad_w2  = (const float*)d_in[10];
    const float* rad_b2  = (const float*)d_in[11];
    const float* rad_g2  = (const float*)d_in[12];
    const float* rad_be2 = (const float*)d_in[13];
    const float* rad_w3  = (const float*)d_in[14];
    const float* rad_b3  = (const float*)d_in[15];
    float* out = (float*)d_out;

    const int N = in_sizes[0] / (19 * 128);   // 32768

    // workspace layout (~162 MB):
    //   [0, 2MB)     wb  : bf16 weights
    //   [2, 10MB)    sh  : xeb -> h2 (8MB)
    //   [10MB, ...)  Aws : bf16 FiLM'd activations [N,19,128] (152MB);
    //                h1 aliases the base (dead before radial3_film writes A)
    __bf16* wb  = (__bf16*)d_ws;
    __bf16* sh  = (__bf16*)((char*)d_ws + (2u << 20));
    __bf16* Aws = (__bf16*)((char*)d_ws + (10u << 20));
    __bf16* h1  = Aws;
    __bf16* wfc0 = wb;
    __bf16* wfc1 = wb + 409600;
    __bf16* wfc2 = wb + 671744;
    __bf16* w1b  = wb + 819200;
    __bf16* w2b  = wb + 835584;
    __bf16* w3b  = wb + 851968;

    wxconv_kernel<<<dim3(5120), dim3(256), 0, stream>>>(fc0_w, fc1_w, fc2_w, rad_w1,
                                                        rad_w2, rad_w3, x_edge, wb, sh);
    gemmln_kernel<<<dim3(N / 128), dim3(256), 0, stream>>>(sh, w1b, rad_b1, rad_g1,
                                                           rad_be1, h1);
    gemmln_kernel<<<dim3(N / 128), dim3(256), 0, stream>>>(h1, w2b, rad_b2, rad_g2,
                                                           rad_be2, sh);
    radial3_film_kernel<<<dim3(N / 128, 12), dim3(256), 0, stream>>>(sh, w3b, rad_b3,
                                                                     x, Aws);
    so2_gemm_kernel<<<dim3(N / 128, 19), dim3(256), 0, stream>>>(Aws, wfc0, wfc1, wfc2,
                                                                 fc0_b, out);
}

// Round 3
// 725.124 us; speedup vs baseline: 1.1820x; 1.0490x over previous
//
#include <hip/hip_runtime.h>

typedef __bf16 bf16x8 __attribute__((ext_vector_type(8)));
typedef __bf16 bf16x4 __attribute__((ext_vector_type(4)));
typedef float f32x4 __attribute__((ext_vector_type(4)));

#define MFMA_16x16x32_BF16(a, b, c) __builtin_amdgcn_mfma_f32_16x16x32_bf16(a, b, c, 0, 0, 0)

typedef const __attribute__((address_space(1))) unsigned int* gas_ptr;
typedef __attribute__((address_space(3))) unsigned int* las_ptr;

__device__ __forceinline__ void gload_lds16(const void* g, void* l) {
    __builtin_amdgcn_global_load_lds((gas_ptr)(unsigned long long)g,
                                     (las_ptr)(unsigned long long)l, 16, 0, 0);
}

// m-major ordering permutation: xm[:, b] = x[:, ORDER[b]]; out[:, ORDER[a]] = gemm_out[:, a]
__constant__ int ORDER_C[19] = {0, 2, 6, 11, 16, 3, 7, 12, 17, 1, 5, 10, 15, 8, 13, 18, 4, 9, 14};

// ---------------------------------------------------------------------------
// Kernel 1: fused weight conversion (1024 blocks) + x_edge conversion (4096).
// ---------------------------------------------------------------------------
__global__ __launch_bounds__(256) void wxconv_kernel(
    const float* __restrict__ fc0, const float* __restrict__ fc1,
    const float* __restrict__ fc2, const float* __restrict__ rw1,
    const float* __restrict__ rw2, const float* __restrict__ rw3,
    const float* __restrict__ xe, __bf16* __restrict__ wo,
    __bf16* __restrict__ xo) {
    const int bid = blockIdx.x;
    const float* s;
    __bf16* o;
    int i4, rel;
    if (bid < 1024) {
        i4 = (bid * 256 + threadIdx.x) * 4;
        o = wo;
        if (i4 < 409600)      { s = fc0; rel = i4; }
        else if (i4 < 671744) { s = fc1; rel = i4 - 409600; }
        else if (i4 < 819200) { s = fc2; rel = i4 - 671744; }
        else if (i4 < 835584) { s = rw1; rel = i4 - 819200; }
        else if (i4 < 851968) { s = rw2; rel = i4 - 835584; }
        else                  { s = rw3; rel = i4 - 851968; }
    } else {
        i4 = ((bid - 1024) * 256 + threadIdx.x) * 4;
        o = xo; s = xe; rel = i4;
    }
    float4 v = *(const float4*)(s + rel);
    bf16x4 b;
    b[0] = (__bf16)v.x; b[1] = (__bf16)v.y; b[2] = (__bf16)v.z; b[3] = (__bf16)v.w;
    *(bf16x4*)(o + i4) = b;
}

// ---------------------------------------------------------------------------
// Kernel 2: fused [64-row tile]@W[128,128]^T + bias + LayerNorm + SiLU -> bf16.
// BM=64 (512 blocks, 2-3 blocks/CU vs 1 at BM=128). 48KB LDS; Fs aliases As+Bs.
// ---------------------------------------------------------------------------
__global__ __launch_bounds__(256) void gemmln_kernel(
    const __bf16* __restrict__ Ain, const __bf16* __restrict__ Wb,
    const float* __restrict__ bvec, const float* __restrict__ gv,
    const float* __restrict__ bev, __bf16* __restrict__ hs) {
    __shared__ __align__(16) char smem[49152];
    __bf16* As = (__bf16*)smem;            // [64][128] bf16, 16KB
    __bf16* Bs = (__bf16*)(smem + 16384);  // [128][128] bf16, 32KB
    float*  Fs = (float*)smem;             // [64][128] f32, 32KB (post-compute alias)
    const int tid = threadIdx.x;
    const int w = tid >> 6, lane = tid & 63;
    const int quad = lane >> 4, l16 = lane & 15;
    const int e0 = blockIdx.x * 64;

    {
        const char* ga = (const char*)(Ain + (size_t)e0 * 128);
        const char* gb = (const char*)Wb;
        for (int r = 0; r < 4; ++r) {
            int boff = (r * 4 + w) * 1024 + lane * 16;
            int soff = boff ^ (((boff >> 8) & 15) << 4);   // pre-swizzled source
            gload_lds16(ga + soff, (char*)As + boff);
        }
        for (int r = 0; r < 8; ++r) {
            int boff = (r * 4 + w) * 1024 + lane * 16;
            int soff = boff ^ (((boff >> 8) & 15) << 4);
            gload_lds16(gb + soff, (char*)Bs + boff);
        }
    }
    __syncthreads();

    const int wr = w >> 1, wc = w & 1;
    f32x4 acc[2][4] = {};
    for (int ks = 0; ks < 4; ++ks) {
        bf16x8 af[2], bfr[4];
        for (int i = 0; i < 2; ++i) {
            int ar = wr * 32 + i * 16 + l16;
            af[i] = *(const bf16x8*)&As[ar * 128 + ((ks * 32 + quad * 8) ^ ((ar & 15) << 3))];
        }
        for (int j = 0; j < 4; ++j) {
            int br = wc * 64 + j * 16 + l16;
            bfr[j] = *(const bf16x8*)&Bs[br * 128 + ((ks * 32 + quad * 8) ^ ((br & 15) << 3))];
        }
        for (int i = 0; i < 2; ++i)
            for (int j = 0; j < 4; ++j)
                acc[i][j] = MFMA_16x16x32_BF16(af[i], bfr[j], acc[i][j]);
    }
    __syncthreads();   // all fragment reads done; smem becomes Fs

    float bc[4];
    for (int j = 0; j < 4; ++j) bc[j] = bvec[wc * 64 + j * 16 + l16];
    for (int i = 0; i < 2; ++i)
        for (int j = 0; j < 4; ++j)
            for (int r = 0; r < 4; ++r)
                Fs[(wr * 32 + i * 16 + quad * 4 + r) * 128 + wc * 64 + j * 16 + l16] =
                    acc[i][j][r] + bc[j];
    __syncthreads();

    const float gl = gv[lane], gh = gv[lane + 64];
    const float bl = bev[lane], bh = bev[lane + 64];
    for (int it = 0; it < 16; ++it) {
        const int row = it * 4 + w;
        float a = Fs[row * 128 + lane];
        float b = Fs[row * 128 + lane + 64];
        float s = a + b;
        s += __shfl_xor(s, 1);  s += __shfl_xor(s, 2);  s += __shfl_xor(s, 4);
        s += __shfl_xor(s, 8);  s += __shfl_xor(s, 16); s += __shfl_xor(s, 32);
        const float mu = s * (1.f / 128.f);
        const float da = a - mu, db = b - mu;
        float v = da * da + db * db;
        v += __shfl_xor(v, 1);  v += __shfl_xor(v, 2);  v += __shfl_xor(v, 4);
        v += __shfl_xor(v, 8);  v += __shfl_xor(v, 16); v += __shfl_xor(v, 32);
        const float rs = rsqrtf(v * (1.f / 128.f) + 1e-5f);
        float ya = da * rs * gl + bl;
        float yb = db * rs * gh + bh;
        ya = ya / (1.f + __expf(-ya));
        yb = yb / (1.f + __expf(-yb));
        hs[(size_t)(e0 + row) * 128 + lane] = (__bf16)ya;
        hs[(size_t)(e0 + row) * 128 + lane + 64] = (__bf16)yb;
    }
}

// ---------------------------------------------------------------------------
// Kernel 3: radial3 + fused FiLM. grid (N/128, 12), 256 thr. (validated r2)
// ---------------------------------------------------------------------------
__global__ __launch_bounds__(256) void radial3_film_kernel(
    const __bf16* __restrict__ h2g, const __bf16* __restrict__ w3b,
    const float* __restrict__ b3, const float* __restrict__ xg,
    __bf16* __restrict__ Aws) {
    __shared__ __align__(16) __bf16 As[128 * 128];
    __shared__ __align__(16) __bf16 Bs[128 * 128];
    const int tid = threadIdx.x;
    const int w = tid >> 6, lane = tid & 63;
    const int quad = lane >> 4, l16 = lane & 15;
    const int y = blockIdx.y;
    const int e0 = blockIdx.x * 128, n0 = y * 128;

    {
        const char* ga = (const char*)(h2g + (size_t)e0 * 128);
        const char* gb = (const char*)(w3b + (size_t)n0 * 128);
        for (int r = 0; r < 8; ++r) {
            int boff = (r * 4 + w) * 1024 + lane * 16;
            int soff = boff ^ (((boff >> 8) & 15) << 4);
            gload_lds16(ga + soff, (char*)As + boff);
            gload_lds16(gb + soff, (char*)Bs + boff);
        }
    }
    __syncthreads();

    const int wr = w >> 1, wc = w & 1;
    f32x4 acc[4][4] = {};
    for (int ks = 0; ks < 4; ++ks) {
        bf16x8 af[4], bfr[4];
        for (int i = 0; i < 4; ++i) {
            int ar = wr * 64 + i * 16 + l16;
            af[i] = *(const bf16x8*)&As[ar * 128 + ((ks * 32 + quad * 8) ^ ((ar & 15) << 3))];
        }
        for (int j = 0; j < 4; ++j) {
            int br = wc * 64 + j * 16 + l16;
            bfr[j] = *(const bf16x8*)&Bs[br * 128 + ((ks * 32 + quad * 8) ^ ((br & 15) << 3))];
        }
        for (int i = 0; i < 4; ++i)
            for (int j = 0; j < 4; ++j)
                acc[i][j] = MFMA_16x16x32_BF16(af[i], bfr[j], acc[i][j]);
    }
    __syncthreads();   // frag reads done; reuse As as rad staging (linear)

    float bcol[4];
    for (int j = 0; j < 4; ++j) bcol[j] = b3[n0 + wc * 64 + j * 16 + l16];
    for (int i = 0; i < 4; ++i)
        for (int j = 0; j < 4; ++j)
            for (int r = 0; r < 4; ++r) {
                int row = wr * 64 + i * 16 + quad * 4 + r;
                int col = wc * 64 + j * 16 + l16;
                As[row * 128 + col] = (__bf16)(acc[i][j][r] + bcol[j]);
            }
    __syncthreads();

    // FiLM epilogue: rad col block n0 feeds coefficient rows (m-major b):
    int nb, bs0, bs1;
    if (y < 5)      { nb = 1; bs0 = y;     bs1 = 0; }
    else if (y < 9) { nb = 2; bs0 = y;     bs1 = y + 4; }
    else            { nb = 2; bs0 = y + 4; bs1 = y + 7; }

    for (int t = 0; t < nb; ++t) {
        const int b = t ? bs1 : bs0;
        const int xrow = ORDER_C[b];
        for (int r = 0; r < 8; ++r) {
            int idx = r * 256 + tid;
            int e = idx >> 4, c = (idx & 15) * 8;
            bf16x8 rv = *(const bf16x8*)&As[e * 128 + c];
            const float* xp = xg + (size_t)(e0 + e) * 2432 + xrow * 128 + c;
            float4 x0 = *(const float4*)xp;
            float4 x1 = *(const float4*)(xp + 4);
            bf16x8 av;
            av[0] = (__bf16)(x0.x * (float)rv[0]);
            av[1] = (__bf16)(x0.y * (float)rv[1]);
            av[2] = (__bf16)(x0.z * (float)rv[2]);
            av[3] = (__bf16)(x0.w * (float)rv[3]);
            av[4] = (__bf16)(x1.x * (float)rv[4]);
            av[5] = (__bf16)(x1.y * (float)rv[5]);
            av[6] = (__bf16)(x1.z * (float)rv[6]);
            av[7] = (__bf16)(x1.w * (float)rv[7]);
            *(bf16x8*)(Aws + (size_t)(e0 + e) * 2432 + b * 128 + c) = av;
        }
    }
}

// ---------------------------------------------------------------------------
// Kernel 4: main GEMM, pure bf16. 1D grid 4864, XCD-chunked (e0,y) mapping
// with y innermost (the 19 blocks sharing an e0's A-slice run adjacently on
// one XCD -> A re-reads are L2 hits). Counted-vmcnt 2-phase pipeline:
// next-tile global_load_lds stays in flight across the MFMA phase (never
// vmcnt(0) in the main loop); fragments pre-read to regs + lgkmcnt(0) before
// the second barrier so staging can overwrite. setprio(1) around MFMA.
// Epilogue staged through LDS -> float4 stores.
// ---------------------------------------------------------------------------
__global__ __launch_bounds__(256, 2) void so2_gemm_kernel(
    const __bf16* __restrict__ Aws, const __bf16* __restrict__ wfc0,
    const __bf16* __restrict__ wfc1, const __bf16* __restrict__ wfc2,
    const float* __restrict__ fc0b, float* __restrict__ outg) {
    __shared__ __align__(16) char smem[65536];   // As[2]:32KB  Bs[2]:32KB ; Fs aliases all
    const int tid = threadIdx.x;
    const int w = tid >> 6, lane = tid & 63;
    const int quad = lane >> 4, l16 = lane & 15;

    // bijective XCD-chunked swizzle: 4864 = 8 XCDs x 608; y innermost
    const int bid = blockIdx.x;
    const int wg = (bid & 7) * 608 + (bid >> 3);
    const int y = wg % 19;
    const int e0 = (wg / 19) * 128;

    int bstart, sz;
    const __bf16* W;
    if (y < 5)       { bstart = 0;  sz = 5; W = wfc0; }
    else if (y < 9)  { bstart = 5;  sz = 4; W = wfc1; }
    else if (y < 13) { bstart = 9;  sz = 4; W = wfc1; }
    else if (y < 16) { bstart = 13; sz = 3; W = wfc2; }
    else             { bstart = 16; sz = 3; W = wfc2; }
    const int K = sz * 128, s_out = y - bstart, nkt = 2 * sz;
    const char* abase = (const char*)Aws + (size_t)bstart * 256;
    const char* wbase = (const char*)W + (size_t)s_out * 128 * K * 2;

#define STAGE(buf, kt)                                                              \
    {                                                                               \
        const char* ak = abase + (size_t)(kt) * 128;                                \
        const char* wk = wbase + (size_t)(kt) * 128;                                \
        char* la = smem + (buf) * 16384;                                            \
        char* lb = smem + 32768 + (buf) * 16384;                                    \
        for (int r = 0; r < 4; ++r) {                                               \
            int boff = (r * 4 + w) * 1024 + lane * 16;                              \
            int row = boff >> 7, kb = boff & 127;                                   \
            int skb = kb ^ ((row & 7) << 4);                                        \
            gload_lds16(ak + (size_t)(e0 + row) * 4864 + skb, la + boff);           \
            gload_lds16(wk + (size_t)row * (size_t)(K * 2) + skb, lb + boff);       \
        }                                                                           \
    }

    const int wr = w >> 1, wc = w & 1;
    f32x4 acc[4][4] = {};
    STAGE(0, 0);
    for (int kt = 0; kt < nkt; ++kt) {
        const int cur = kt & 1;
        if (kt + 1 < nkt) {
            STAGE(cur ^ 1, kt + 1);
            asm volatile("s_waitcnt vmcnt(8)" ::: "memory");  // cur's 8 loads done; next 8 in flight
        } else {
            asm volatile("s_waitcnt vmcnt(0)" ::: "memory");
        }
        __builtin_amdgcn_s_barrier();        // cur buffer published to all waves

        const __bf16* Asc = (const __bf16*)(smem + cur * 16384);
        const __bf16* Bsc = (const __bf16*)(smem + 32768 + cur * 16384);
        bf16x8 af[2][4], bfr[2][4];
        for (int ks = 0; ks < 2; ++ks) {
            for (int i = 0; i < 4; ++i) {
                int ar = wr * 64 + i * 16 + l16;
                af[ks][i] = *(const bf16x8*)&Asc[ar * 64 + ((ks * 32 + quad * 8) ^ ((ar & 7) << 3))];
            }
            for (int j = 0; j < 4; ++j) {
                int br = wc * 64 + j * 16 + l16;
                bfr[ks][j] = *(const bf16x8*)&Bsc[br * 64 + ((ks * 32 + quad * 8) ^ ((br & 7) << 3))];
            }
        }
        asm volatile("s_waitcnt lgkmcnt(0)" ::: "memory");  // reads retired: cur may be overwritten
        __builtin_amdgcn_s_barrier();

        __builtin_amdgcn_s_setprio(1);
        for (int ks = 0; ks < 2; ++ks)
            for (int i = 0; i < 4; ++i)
                for (int j = 0; j < 4; ++j)
                    acc[i][j] = MFMA_16x16x32_BF16(af[ks][i], bfr[ks][j], acc[i][j]);
        __builtin_amdgcn_s_setprio(0);
    }
#undef STAGE

    // epilogue: bias (m0 only), stage fp32 C tile in LDS, float4 stores
    const int outrow = ORDER_C[y];
    float bv[4];
    for (int j = 0; j < 4; ++j)
        bv[j] = (y < 5) ? fc0b[s_out * 128 + wc * 64 + j * 16 + l16] : 0.f;
    float* Fs = (float*)smem;   // [128][128] f32 = 64KB
    for (int i = 0; i < 4; ++i)
        for (int j = 0; j < 4; ++j)
            for (int r = 0; r < 4; ++r)
                Fs[(wr * 64 + i * 16 + quad * 4 + r) * 128 + wc * 64 + j * 16 + l16] =
                    acc[i][j][r] + bv[j];
    __syncthreads();
    for (int t = 0; t < 16; ++t) {
        int idx = t * 256 + tid;
        int row = idx >> 5, c4 = (idx & 31) * 4;
        *(float4*)(outg + (size_t)(e0 + row) * 2432 + outrow * 128 + c4) =
            *(const float4*)&Fs[row * 128 + c4];
    }
}

// ---------------------------------------------------------------------------
extern "C" void kernel_launch(void* const* d_in, const int* in_sizes, int n_in,
                              void* d_out, int out_size, void* d_ws, size_t ws_size,
                              hipStream_t stream) {
    const float* x       = (const float*)d_in[0];
    const float* x_edge  = (const float*)d_in[1];
    const float* fc0_w   = (const float*)d_in[2];
    const float* fc0_b   = (const float*)d_in[3];
    const float* fc1_w   = (const float*)d_in[4];
    const float* fc2_w   = (const float*)d_in[5];
    const float* rad_w1  = (const float*)d_in[6];
    const float* rad_b1  = (const float*)d_in[7];
    const float* rad_g1  = (const float*)d_in[8];
    const float* rad_be1 = (const float*)d_in[9];
    const float* rad_w2  = (const float*)d_in[10];
    const float* rad_b2  = (const float*)d_in[11];
    const float* rad_g2  = (const float*)d_in[12];
    const float* rad_be2 = (const float*)d_in[13];
    const float* rad_w3  = (const float*)d_in[14];
    const float* rad_b3  = (const float*)d_in[15];
    float* out = (float*)d_out;

    const int N = in_sizes[0] / (19 * 128);   // 32768

    // workspace layout (~162 MB):
    //   [0, 2MB)     wb  : bf16 weights
    //   [2, 10MB)    sh  : xeb -> h2 (8MB)
    //   [10MB, ...)  Aws : bf16 FiLM'd activations [N,19,128] (152MB);
    //                h1 aliases the base (dead before radial3_film writes A)
    __bf16* wb  = (__bf16*)d_ws;
    __bf16* sh  = (__bf16*)((char*)d_ws + (2u << 20));
    __bf16* Aws = (__bf16*)((char*)d_ws + (10u << 20));
    __bf16* h1  = Aws;
    __bf16* wfc0 = wb;
    __bf16* wfc1 = wb + 409600;
    __bf16* wfc2 = wb + 671744;
    __bf16* w1b  = wb + 819200;
    __bf16* w2b  = wb + 835584;
    __bf16* w3b  = wb + 851968;

    wxconv_kernel<<<dim3(5120), dim3(256), 0, stream>>>(fc0_w, fc1_w, fc2_w, rad_w1,
                                                        rad_w2, rad_w3, x_edge, wb, sh);
    gemmln_kernel<<<dim3(N / 64), dim3(256), 0, stream>>>(sh, w1b, rad_b1, rad_g1,
                                                          rad_be1, h1);
    gemmln_kernel<<<dim3(N / 64), dim3(256), 0, stream>>>(h1, w2b, rad_b2, rad_g2,
                                                          rad_be2, sh);
    radial3_film_kernel<<<dim3(N / 128, 12), dim3(256), 0, stream>>>(sh, w3b, rad_b3,
                                                                     x, Aws);
    so2_gemm_kernel<<<dim3(8 * 608), dim3(256), 0, stream>>>(Aws, wfc0, wfc1, wfc2,
                                                             fc0_b, out);
}

// Round 4
// 722.150 us; speedup vs baseline: 1.1868x; 1.0041x over previous
//
#include <hip/hip_runtime.h>

typedef __bf16 bf16x8 __attribute__((ext_vector_type(8)));
typedef __bf16 bf16x4 __attribute__((ext_vector_type(4)));
typedef float f32x4 __attribute__((ext_vector_type(4)));

#define MFMA_16x16x32_BF16(a, b, c) __builtin_amdgcn_mfma_f32_16x16x32_bf16(a, b, c, 0, 0, 0)

typedef const __attribute__((address_space(1))) unsigned int* gas_ptr;
typedef __attribute__((address_space(3))) unsigned int* las_ptr;

__device__ __forceinline__ void gload_lds16(const void* g, void* l) {
    __builtin_amdgcn_global_load_lds((gas_ptr)(unsigned long long)g,
                                     (las_ptr)(unsigned long long)l, 16, 0, 0);
}

// m-major ordering permutation: xm[:, b] = x[:, ORDER[b]]; out[:, ORDER[a]] = gemm_out[:, a]
__constant__ int ORDER_C[19] = {0, 2, 6, 11, 16, 3, 7, 12, 17, 1, 5, 10, 15, 8, 13, 18, 4, 9, 14};

// ---------------------------------------------------------------------------
// Kernel 1: fused weight conversion (1024 blocks) + x_edge conversion (4096).
// ---------------------------------------------------------------------------
__global__ __launch_bounds__(256) void wxconv_kernel(
    const float* __restrict__ fc0, const float* __restrict__ fc1,
    const float* __restrict__ fc2, const float* __restrict__ rw1,
    const float* __restrict__ rw2, const float* __restrict__ rw3,
    const float* __restrict__ xe, __bf16* __restrict__ wo,
    __bf16* __restrict__ xo) {
    const int bid = blockIdx.x;
    const float* s;
    __bf16* o;
    int i4, rel;
    if (bid < 1024) {
        i4 = (bid * 256 + threadIdx.x) * 4;
        o = wo;
        if (i4 < 409600)      { s = fc0; rel = i4; }
        else if (i4 < 671744) { s = fc1; rel = i4 - 409600; }
        else if (i4 < 819200) { s = fc2; rel = i4 - 671744; }
        else if (i4 < 835584) { s = rw1; rel = i4 - 819200; }
        else if (i4 < 851968) { s = rw2; rel = i4 - 835584; }
        else                  { s = rw3; rel = i4 - 851968; }
    } else {
        i4 = ((bid - 1024) * 256 + threadIdx.x) * 4;
        o = xo; s = xe; rel = i4;
    }
    float4 v = *(const float4*)(s + rel);
    bf16x4 b;
    b[0] = (__bf16)v.x; b[1] = (__bf16)v.y; b[2] = (__bf16)v.z; b[3] = (__bf16)v.w;
    *(bf16x4*)(o + i4) = b;
}

// ---------------------------------------------------------------------------
// Kernel 2: BOTH radial MLP layers in one kernel. Per block: 64-edge tile.
// h1 = silu(LN(xe@W1^T+b1)) stays in LDS (never touches HBM); W2 staged into
// Bs after the post-GEMM1 barrier; h2 = silu(LN(h1@W2^T+b2)) -> global bf16.
// LDS: As 16KB @0, Bs 32KB @16K, Fs 32KB @48K  (80KB -> 2 blocks/CU).
// ---------------------------------------------------------------------------
__global__ __launch_bounds__(256) void radial12_kernel(
    const __bf16* __restrict__ xeb, const __bf16* __restrict__ w1b,
    const __bf16* __restrict__ w2b,
    const float* __restrict__ b1, const float* __restrict__ g1,
    const float* __restrict__ be1,
    const float* __restrict__ b2, const float* __restrict__ g2,
    const float* __restrict__ be2, __bf16* __restrict__ h2out) {
    __shared__ __align__(16) char smem[81920];
    __bf16* As = (__bf16*)smem;            // [64][128] bf16
    __bf16* Bs = (__bf16*)(smem + 16384);  // [128][128] bf16
    float*  Fs = (float*)(smem + 49152);   // [64][128] f32
    const int tid = threadIdx.x;
    const int w = tid >> 6, lane = tid & 63;
    const int quad = lane >> 4, l16 = lane & 15;
    const int e0 = blockIdx.x * 64;
    const int wr = w >> 1, wc = w & 1;

    {   // stage xe tile + W1 (pre-swizzled source, linear LDS dest)
        const char* ga = (const char*)(xeb + (size_t)e0 * 128);
        const char* gb = (const char*)w1b;
        for (int r = 0; r < 4; ++r) {
            int boff = (r * 4 + w) * 1024 + lane * 16;
            int soff = boff ^ (((boff >> 8) & 15) << 4);
            gload_lds16(ga + soff, (char*)As + boff);
        }
        for (int r = 0; r < 8; ++r) {
            int boff = (r * 4 + w) * 1024 + lane * 16;
            int soff = boff ^ (((boff >> 8) & 15) << 4);
            gload_lds16(gb + soff, (char*)Bs + boff);
        }
    }
    __syncthreads();

    // ---- GEMM layer 1
    f32x4 acc[2][4] = {};
    for (int ks = 0; ks < 4; ++ks) {
        bf16x8 af[2], bfr[4];
        for (int i = 0; i < 2; ++i) {
            int ar = wr * 32 + i * 16 + l16;
            af[i] = *(const bf16x8*)&As[ar * 128 + ((ks * 32 + quad * 8) ^ ((ar & 15) << 3))];
        }
        for (int j = 0; j < 4; ++j) {
            int br = wc * 64 + j * 16 + l16;
            bfr[j] = *(const bf16x8*)&Bs[br * 128 + ((ks * 32 + quad * 8) ^ ((br & 15) << 3))];
        }
        for (int i = 0; i < 2; ++i)
            for (int j = 0; j < 4; ++j)
                acc[i][j] = MFMA_16x16x32_BF16(af[i], bfr[j], acc[i][j]);
    }
    __syncthreads();   // all As/Bs reads retired

    {   // prefetch W2 into Bs (flies during Fs write + LN1)
        const char* gb = (const char*)w2b;
        for (int r = 0; r < 8; ++r) {
            int boff = (r * 4 + w) * 1024 + lane * 16;
            int soff = boff ^ (((boff >> 8) & 15) << 4);
            gload_lds16(gb + soff, (char*)Bs + boff);
        }
    }

    {   // bias + stage fp32 in Fs
        float bc[4];
        for (int j = 0; j < 4; ++j) bc[j] = b1[wc * 64 + j * 16 + l16];
        for (int i = 0; i < 2; ++i)
            for (int j = 0; j < 4; ++j)
                for (int r = 0; r < 4; ++r)
                    Fs[(wr * 32 + i * 16 + quad * 4 + r) * 128 + wc * 64 + j * 16 + l16] =
                        acc[i][j][r] + bc[j];
    }
    __syncthreads();

    {   // LN1 + SiLU -> h1 bf16 into As (swizzled, consumed by GEMM2)
        const float gl = g1[lane], gh = g1[lane + 64];
        const float bl = be1[lane], bh = be1[lane + 64];
        for (int it = 0; it < 16; ++it) {
            const int row = it * 4 + w;
            float a = Fs[row * 128 + lane];
            float b = Fs[row * 128 + lane + 64];
            float s = a + b;
            s += __shfl_xor(s, 1);  s += __shfl_xor(s, 2);  s += __shfl_xor(s, 4);
            s += __shfl_xor(s, 8);  s += __shfl_xor(s, 16); s += __shfl_xor(s, 32);
            const float mu = s * (1.f / 128.f);
            const float da = a - mu, db = b - mu;
            float v = da * da + db * db;
            v += __shfl_xor(v, 1);  v += __shfl_xor(v, 2);  v += __shfl_xor(v, 4);
            v += __shfl_xor(v, 8);  v += __shfl_xor(v, 16); v += __shfl_xor(v, 32);
            const float rs = rsqrtf(v * (1.f / 128.f) + 1e-5f);
            float ya = da * rs * gl + bl;
            float yb = db * rs * gh + bh;
            ya = ya / (1.f + __expf(-ya));
            yb = yb / (1.f + __expf(-yb));
            As[row * 128 + (lane ^ ((row & 15) << 3))] = (__bf16)ya;
            As[row * 128 + ((lane + 64) ^ ((row & 15) << 3))] = (__bf16)yb;
        }
    }
    __syncthreads();   // h1 visible; syncthreads' vmcnt(0) drain => W2 landed

    // ---- GEMM layer 2
    f32x4 acc2[2][4] = {};
    for (int ks = 0; ks < 4; ++ks) {
        bf16x8 af[2], bfr[4];
        for (int i = 0; i < 2; ++i) {
            int ar = wr * 32 + i * 16 + l16;
            af[i] = *(const bf16x8*)&As[ar * 128 + ((ks * 32 + quad * 8) ^ ((ar & 15) << 3))];
        }
        for (int j = 0; j < 4; ++j) {
            int br = wc * 64 + j * 16 + l16;
            bfr[j] = *(const bf16x8*)&Bs[br * 128 + ((ks * 32 + quad * 8) ^ ((br & 15) << 3))];
        }
        for (int i = 0; i < 2; ++i)
            for (int j = 0; j < 4; ++j)
                acc2[i][j] = MFMA_16x16x32_BF16(af[i], bfr[j], acc2[i][j]);
    }

    {   // bias2 -> Fs (no barrier needed: Fs last READ before pre-GEMM2 sync)
        float bc[4];
        for (int j = 0; j < 4; ++j) bc[j] = b2[wc * 64 + j * 16 + l16];
        for (int i = 0; i < 2; ++i)
            for (int j = 0; j < 4; ++j)
                for (int r = 0; r < 4; ++r)
                    Fs[(wr * 32 + i * 16 + quad * 4 + r) * 128 + wc * 64 + j * 16 + l16] =
                        acc2[i][j][r] + bc[j];
    }
    __syncthreads();

    {   // LN2 + SiLU -> h2 global bf16
        const float gl = g2[lane], gh = g2[lane + 64];
        const float bl = be2[lane], bh = be2[lane + 64];
        for (int it = 0; it < 16; ++it) {
            const int row = it * 4 + w;
            float a = Fs[row * 128 + lane];
            float b = Fs[row * 128 + lane + 64];
            float s = a + b;
            s += __shfl_xor(s, 1);  s += __shfl_xor(s, 2);  s += __shfl_xor(s, 4);
            s += __shfl_xor(s, 8);  s += __shfl_xor(s, 16); s += __shfl_xor(s, 32);
            const float mu = s * (1.f / 128.f);
            const float da = a - mu, db = b - mu;
            float v = da * da + db * db;
            v += __shfl_xor(v, 1);  v += __shfl_xor(v, 2);  v += __shfl_xor(v, 4);
            v += __shfl_xor(v, 8);  v += __shfl_xor(v, 16); v += __shfl_xor(v, 32);
            const float rs = rsqrtf(v * (1.f / 128.f) + 1e-5f);
            float ya = da * rs * gl + bl;
            float yb = db * rs * gh + bh;
            ya = ya / (1.f + __expf(-ya));
            yb = yb / (1.f + __expf(-yb));
            h2out[(size_t)(e0 + row) * 128 + lane] = (__bf16)ya;
            h2out[(size_t)(e0 + row) * 128 + lane + 64] = (__bf16)yb;
        }
    }
}

// ---------------------------------------------------------------------------
// Kernel 3: radial3 + fused FiLM. grid (N/128, 12), 256 thr. (validated r2/r3)
// ---------------------------------------------------------------------------
__global__ __launch_bounds__(256) void radial3_film_kernel(
    const __bf16* __restrict__ h2g, const __bf16* __restrict__ w3b,
    const float* __restrict__ b3, const float* __restrict__ xg,
    __bf16* __restrict__ Aws) {
    __shared__ __align__(16) __bf16 As[128 * 128];
    __shared__ __align__(16) __bf16 Bs[128 * 128];
    const int tid = threadIdx.x;
    const int w = tid >> 6, lane = tid & 63;
    const int quad = lane >> 4, l16 = lane & 15;
    const int y = blockIdx.y;
    const int e0 = blockIdx.x * 128, n0 = y * 128;

    {
        const char* ga = (const char*)(h2g + (size_t)e0 * 128);
        const char* gb = (const char*)(w3b + (size_t)n0 * 128);
        for (int r = 0; r < 8; ++r) {
            int boff = (r * 4 + w) * 1024 + lane * 16;
            int soff = boff ^ (((boff >> 8) & 15) << 4);
            gload_lds16(ga + soff, (char*)As + boff);
            gload_lds16(gb + soff, (char*)Bs + boff);
        }
    }
    __syncthreads();

    const int wr = w >> 1, wc = w & 1;
    f32x4 acc[4][4] = {};
    for (int ks = 0; ks < 4; ++ks) {
        bf16x8 af[4], bfr[4];
        for (int i = 0; i < 4; ++i) {
            int ar = wr * 64 + i * 16 + l16;
            af[i] = *(const bf16x8*)&As[ar * 128 + ((ks * 32 + quad * 8) ^ ((ar & 15) << 3))];
        }
        for (int j = 0; j < 4; ++j) {
            int br = wc * 64 + j * 16 + l16;
            bfr[j] = *(const bf16x8*)&Bs[br * 128 + ((ks * 32 + quad * 8) ^ ((br & 15) << 3))];
        }
        for (int i = 0; i < 4; ++i)
            for (int j = 0; j < 4; ++j)
                acc[i][j] = MFMA_16x16x32_BF16(af[i], bfr[j], acc[i][j]);
    }
    __syncthreads();   // frag reads done; reuse As as rad staging (linear)

    float bcol[4];
    for (int j = 0; j < 4; ++j) bcol[j] = b3[n0 + wc * 64 + j * 16 + l16];
    for (int i = 0; i < 4; ++i)
        for (int j = 0; j < 4; ++j)
            for (int r = 0; r < 4; ++r) {
                int row = wr * 64 + i * 16 + quad * 4 + r;
                int col = wc * 64 + j * 16 + l16;
                As[row * 128 + col] = (__bf16)(acc[i][j][r] + bcol[j]);
            }
    __syncthreads();

    // FiLM epilogue: rad col block n0 feeds coefficient rows (m-major b):
    int nb, bs0, bs1;
    if (y < 5)      { nb = 1; bs0 = y;     bs1 = 0; }
    else if (y < 9) { nb = 2; bs0 = y;     bs1 = y + 4; }
    else            { nb = 2; bs0 = y + 4; bs1 = y + 7; }

    for (int t = 0; t < nb; ++t) {
        const int b = t ? bs1 : bs0;
        const int xrow = ORDER_C[b];
        for (int r = 0; r < 8; ++r) {
            int idx = r * 256 + tid;
            int e = idx >> 4, c = (idx & 15) * 8;
            bf16x8 rv = *(const bf16x8*)&As[e * 128 + c];
            const float* xp = xg + (size_t)(e0 + e) * 2432 + xrow * 128 + c;
            float4 x0 = *(const float4*)xp;
            float4 x1 = *(const float4*)(xp + 4);
            bf16x8 av;
            av[0] = (__bf16)(x0.x * (float)rv[0]);
            av[1] = (__bf16)(x0.y * (float)rv[1]);
            av[2] = (__bf16)(x0.z * (float)rv[2]);
            av[3] = (__bf16)(x0.w * (float)rv[3]);
            av[4] = (__bf16)(x1.x * (float)rv[4]);
            av[5] = (__bf16)(x1.y * (float)rv[5]);
            av[6] = (__bf16)(x1.z * (float)rv[6]);
            av[7] = (__bf16)(x1.w * (float)rv[7]);
            *(bf16x8*)(Aws + (size_t)(e0 + e) * 2432 + b * 128 + c) = av;
        }
    }
}

// ---------------------------------------------------------------------------
// Kernel 4: main GEMM, BM=256, 512 threads (8 waves, 4Mx2N), 3-deep LDS
// pipeline (144KB: A 3x32KB @0, B 3x16KB @98304). Steady-state vmcnt(12)
// keeps 2 full tiles (12 loads) in flight -> covers ~900cy HBM latency with
// only 1 block/CU. XCD-chunked 1D grid, y innermost (the 19 y's sharing an
// e0 A-slice run adjacently on one XCD -> A re-reads are L2 hits).
// ---------------------------------------------------------------------------
__global__ __launch_bounds__(512, 1) void so2_gemm_kernel(
    const __bf16* __restrict__ Aws, const __bf16* __restrict__ wfc0,
    const __bf16* __restrict__ wfc1, const __bf16* __restrict__ wfc2,
    const float* __restrict__ fc0b, float* __restrict__ outg) {
    __shared__ __align__(16) char smem[147456];
    const int tid = threadIdx.x;
    const int w = tid >> 6, lane = tid & 63;
    const int quad = lane >> 4, l16 = lane & 15;

    // bijective XCD-chunked swizzle: 2432 = 8 XCDs x 304; y innermost (304=16*19)
    const int bid = blockIdx.x;
    const int wg = (bid & 7) * 304 + (bid >> 3);
    const int y = wg % 19;
    const int e0 = (wg / 19) * 256;

    int bstart, sz;
    const __bf16* W;
    if (y < 5)       { bstart = 0;  sz = 5; W = wfc0; }
    else if (y < 9)  { bstart = 5;  sz = 4; W = wfc1; }
    else if (y < 13) { bstart = 9;  sz = 4; W = wfc1; }
    else if (y < 16) { bstart = 13; sz = 3; W = wfc2; }
    else             { bstart = 16; sz = 3; W = wfc2; }
    const int K = sz * 128, s_out = y - bstart, nkt = 2 * sz;
    const char* abase = (const char*)Aws + (size_t)bstart * 256;
    const char* wbase = (const char*)W + (size_t)s_out * 128 * K * 2;

#define STAGE(buf, kt)                                                              \
    {                                                                               \
        const char* ak = abase + (size_t)(kt) * 128;                                \
        const char* wk = wbase + (size_t)(kt) * 128;                                \
        char* la = smem + (buf) * 32768;                                            \
        char* lb = smem + 98304 + (buf) * 16384;                                    \
        for (int r = 0; r < 4; ++r) {                                               \
            int boff = (r * 8 + w) * 1024 + lane * 16;                              \
            int row = boff >> 7, kb = boff & 127;                                   \
            int skb = kb ^ ((row & 7) << 4);                                        \
            gload_lds16(ak + (size_t)(e0 + row) * 4864 + skb, la + boff);           \
        }                                                                           \
        for (int r = 0; r < 2; ++r) {                                               \
            int boff = (r * 8 + w) * 1024 + lane * 16;                              \
            int row = boff >> 7, kb = boff & 127;                                   \
            int skb = kb ^ ((row & 7) << 4);                                        \
            gload_lds16(wk + (size_t)row * (size_t)(K * 2) + skb, lb + boff);       \
        }                                                                           \
    }

    const int wr = w >> 1, wc = w & 1;
    f32x4 acc[4][4] = {};
    STAGE(0, 0);
    STAGE(1, 1);
    int cur = 0;
    for (int kt = 0; kt < nkt; ++kt) {
        if (kt + 2 < nkt) {
            const int nb = (cur == 0) ? 2 : (cur == 1 ? 0 : 1);   // (kt+2)%3
            STAGE(nb, kt + 2);
            asm volatile("s_waitcnt vmcnt(12)" ::: "memory");  // tile kt done; 2 tiles in flight
        } else if (kt + 1 < nkt) {
            asm volatile("s_waitcnt vmcnt(6)" ::: "memory");
        } else {
            asm volatile("s_waitcnt vmcnt(0)" ::: "memory");
        }
        __builtin_amdgcn_s_barrier();        // tile kt published to all waves

        const __bf16* Asc = (const __bf16*)(smem + cur * 32768);
        const __bf16* Bsc = (const __bf16*)(smem + 98304 + cur * 16384);
        bf16x8 af[2][4], bfr[2][4];
        for (int ks = 0; ks < 2; ++ks) {
            for (int i = 0; i < 4; ++i) {
                int ar = wr * 64 + i * 16 + l16;
                af[ks][i] = *(const bf16x8*)&Asc[ar * 64 + ((ks * 32 + quad * 8) ^ ((ar & 7) << 3))];
            }
            for (int j = 0; j < 4; ++j) {
                int br = wc * 64 + j * 16 + l16;
                bfr[ks][j] = *(const bf16x8*)&Bsc[br * 64 + ((ks * 32 + quad * 8) ^ ((br & 7) << 3))];
            }
        }
        asm volatile("s_waitcnt lgkmcnt(0)" ::: "memory");  // reads retired; buffer reusable
        __builtin_amdgcn_s_barrier();

        __builtin_amdgcn_s_setprio(1);
        for (int ks = 0; ks < 2; ++ks)
            for (int i = 0; i < 4; ++i)
                for (int j = 0; j < 4; ++j)
                    acc[i][j] = MFMA_16x16x32_BF16(af[ks][i], bfr[ks][j], acc[i][j]);
        __builtin_amdgcn_s_setprio(0);
        cur = (cur == 2) ? 0 : cur + 1;
    }
#undef STAGE

    // epilogue: bias (m0 only); two-pass fp32 LDS stage (Fs 64KB aliases bufs)
    const int outrow = ORDER_C[y];
    float bv[4];
    for (int j = 0; j < 4; ++j)
        bv[j] = (y < 5) ? fc0b[s_out * 128 + wc * 64 + j * 16 + l16] : 0.f;
    float* Fs = (float*)smem;
    for (int p = 0; p < 2; ++p) {
        if ((wr >> 1) == p) {
            for (int i = 0; i < 4; ++i)
                for (int j = 0; j < 4; ++j)
                    for (int r = 0; r < 4; ++r)
                        Fs[((wr & 1) * 64 + i * 16 + quad * 4 + r) * 128 + wc * 64 + j * 16 + l16] =
                            acc[i][j][r] + bv[j];
        }
        __syncthreads();
        for (int t = 0; t < 8; ++t) {
            int idx = t * 512 + tid;
            int row = idx >> 5, c4 = (idx & 31) * 4;
            *(float4*)(outg + (size_t)(e0 + p * 128 + row) * 2432 + outrow * 128 + c4) =
                *(const float4*)&Fs[row * 128 + c4];
        }
        if (p == 0) __syncthreads();
    }
}

// ---------------------------------------------------------------------------
extern "C" void kernel_launch(void* const* d_in, const int* in_sizes, int n_in,
                              void* d_out, int out_size, void* d_ws, size_t ws_size,
                              hipStream_t stream) {
    const float* x       = (const float*)d_in[0];
    const float* x_edge  = (const float*)d_in[1];
    const float* fc0_w   = (const float*)d_in[2];
    const float* fc0_b   = (const float*)d_in[3];
    const float* fc1_w   = (const float*)d_in[4];
    const float* fc2_w   = (const float*)d_in[5];
    const float* rad_w1  = (const float*)d_in[6];
    const float* rad_b1  = (const float*)d_in[7];
    const float* rad_g1  = (const float*)d_in[8];
    const float* rad_be1 = (const float*)d_in[9];
    const float* rad_w2  = (const float*)d_in[10];
    const float* rad_b2  = (const float*)d_in[11];
    const float* rad_g2  = (const float*)d_in[12];
    const float* rad_be2 = (const float*)d_in[13];
    const float* rad_w3  = (const float*)d_in[14];
    const float* rad_b3  = (const float*)d_in[15];
    float* out = (float*)d_out;

    const int N = in_sizes[0] / (19 * 128);   // 32768

    // workspace layout (~170 MB):
    //   [0, 2MB)    wb  : bf16 weights
    //   [2, 10MB)   xeb : x_edge bf16 (8MB)
    //   [10,18MB)   h2  : radial MLP output bf16 (8MB)
    //   [18MB, ...) Aws : bf16 FiLM'd activations [N,19,128] (152MB)
    __bf16* wb  = (__bf16*)d_ws;
    __bf16* xeb = (__bf16*)((char*)d_ws + (2u << 20));
    __bf16* h2  = (__bf16*)((char*)d_ws + (10u << 20));
    __bf16* Aws = (__bf16*)((char*)d_ws + (18u << 20));
    __bf16* wfc0 = wb;
    __bf16* wfc1 = wb + 409600;
    __bf16* wfc2 = wb + 671744;
    __bf16* w1b  = wb + 819200;
    __bf16* w2b  = wb + 835584;
    __bf16* w3b  = wb + 851968;

    wxconv_kernel<<<dim3(5120), dim3(256), 0, stream>>>(fc0_w, fc1_w, fc2_w, rad_w1,
                                                        rad_w2, rad_w3, x_edge, wb, xeb);
    radial12_kernel<<<dim3(N / 64), dim3(256), 0, stream>>>(
        xeb, w1b, w2b, rad_b1, rad_g1, rad_be1, rad_b2, rad_g2, rad_be2, h2);
    radial3_film_kernel<<<dim3(N / 128, 12), dim3(256), 0, stream>>>(h2, w3b, rad_b3,
                                                                     x, Aws);
    so2_gemm_kernel<<<dim3(2432), dim3(512), 0, stream>>>(Aws, wfc0, wfc1, wfc2,
                                                          fc0_b, out);
}